// Round 4
// baseline (278.876 us; speedup 1.0000x reference)
//
#include <hip/hip_runtime.h>
#include <hip/hip_bf16.h>

// DeformableConv1D: B=4, Cin=256, Cout=256, L=8192, K=7, stride=1, pad=3, dil=1
// out[b,o,l] = sum_{i,kt} w[o,i,kt] * interp(b, l, i, kt) + bias[o]
// loc[b,l,kt] = l + kt + (offset_conv(x)[b,l,kt] + offset_b[kt])
// interp = wa*x[b,i,x0c] + wb*x[b,i,x1c]  (clamped lerp, reference formula)
//
// GEMM: C[o,n] = sum_q A[o][q]*B[q][n], n = b*8192+l, q = kt*256 + i.
// Main kernel: 7 tap-chunks (kt compile-time). Per chunk: stage interp
// (64n x 256i) to LDS in one burst (128 loads/thread), then 8 MFMA K-steps.
// 2 barriers/chunk (14 total vs 112 in round 2).
// i-mapping: i = 32*j + 8*w + m  (fixes round-3 OOB LDS write).

#define B_    4
#define CIN   256
#define COUT  256
#define LEN   8192
#define KK    7
#define NTOT  (B_ * LEN)          // 32768
#define QTOT  (CIN * KK)          // 1792
#define LPITCH 264                // LDS row pitch (elems): 528 B

typedef short s16x8 __attribute__((ext_vector_type(8)));
typedef float f32x4 __attribute__((ext_vector_type(4)));

static __device__ __forceinline__ unsigned short f2bf(float f) {
  union { float f; unsigned u; } u; u.f = f;
  unsigned r = u.u + 0x7FFF + ((u.u >> 16) & 1);   // RNE (finite inputs)
  return (unsigned short)(r >> 16);
}

// ---------------------------------------------------------------------------
// Kernel 1: Loc[n*7+k] = (l + k) + OB[k]  (base; loc_partial atomically adds)
// ---------------------------------------------------------------------------
__global__ __launch_bounds__(256) void init_loc(
    const float* __restrict__ OB, float* __restrict__ Loc) {
  int id = blockIdx.x * 256 + threadIdx.x;     // grid 896
  int n = id / 7;
  int k = id - n * 7;
  int l = n & (LEN - 1);
  Loc[id] = (float)(l + k) + OB[k];
}

// ---------------------------------------------------------------------------
// Kernel 2: offset conv partials. 16 channel-groups of 16, atomicAdd into Loc.
// grid = 128*16 = 2048 blocks; g block-uniform -> OW via s_loads.
// ---------------------------------------------------------------------------
__global__ __launch_bounds__(256) void loc_partial(
    const float* __restrict__ X, const float* __restrict__ OW,
    float* __restrict__ Loc) {
  int g = blockIdx.x >> 7;                               // 0..15
  int n = ((blockIdx.x & 127) << 8) + threadIdx.x;       // 0..32767
  int b = n >> 13;
  int l = n & (LEN - 1);
  const float* xb = X + ((size_t)b << 21);

  float acc[KK];
#pragma unroll
  for (int k = 0; k < KK; ++k) acc[k] = 0.0f;

  for (int i = g * 16; i < g * 16 + 16; ++i) {
    const float* xr = xb + ((size_t)i << 13);
    float xv[KK];
#pragma unroll
    for (int j = 0; j < KK; ++j) {
      int pos = l + j - 3;
      xv[j] = ((unsigned)pos < LEN) ? xr[pos] : 0.0f;
    }
#pragma unroll
    for (int k = 0; k < KK; ++k)
#pragma unroll
      for (int j = 0; j < KK; ++j)
        acc[k] += xv[j] * OW[(k * CIN + i) * KK + j];    // uniform -> s_load
  }
#pragma unroll
  for (int k = 0; k < KK; ++k)
    atomicAdd(Loc + (size_t)n * KK + k, acc[k]);
}

// ---------------------------------------------------------------------------
// Kernel 3: weights -> bf16 A-fragments, per-lane MFMA order.
// frag = ((ot*7 + kt)*8 + s); elem lane*8+j holds
//   W[o = ot*16 + (lane&15)][(i = s*32 + (lane>>4)*8 + j)*7 + kt]
// ---------------------------------------------------------------------------
__global__ __launch_bounds__(256) void wt_build(
    const float* __restrict__ W, unsigned short* __restrict__ Wf) {
  int tid  = blockIdx.x * 256 + threadIdx.x;   // grid 224 -> 57344
  int lane = tid & 63;
  int frag = tid >> 6;
  int s    = frag & 7;
  int okt  = frag >> 3;
  int kt   = okt % KK;
  int ot   = okt / KK;
  int o    = ot * 16 + (lane & 15);
  int ib   = s * 32 + (lane >> 4) * 8;
  s16x8 v;
#pragma unroll
  for (int j = 0; j < 8; ++j)
    v[j] = (short)f2bf(W[(size_t)o * QTOT + (ib + j) * KK + kt]);
  *(s16x8*)(Wf + (size_t)tid * 8) = v;
}

// ---------------------------------------------------------------------------
// Kernel 4: main MFMA GEMM. Block = 256(o) x 64(n), 4 waves, grid 512.
// Per tap-chunk kt: stage interp[64 n][256 i] -> LDS (each thread 64 elems:
// i = 32*j + 8*w + m, j<8, m<8; 128 coalesced-ish loads, 8 b128 LDS writes),
// barrier, 8 MFMA K-steps (4 nt x 4 tt mfma_16x16x32 each), barrier.
// ---------------------------------------------------------------------------
__global__ __launch_bounds__(256, 2) void main_kernel(
    const float* __restrict__ X, const unsigned short* __restrict__ Wf,
    const float* __restrict__ Bias, const float* __restrict__ Loc,
    float* __restrict__ Out) {
  __shared__ unsigned short Il[64][LPITCH];    // 33792 B

  const int t    = threadIdx.x;
  const int lane = t & 63;
  const int w    = t >> 6;
  const int n0   = blockIdx.x << 6;            // grid 512
  const int b    = n0 >> 13;
  const float* Xb = X + ((size_t)b << 21);

  // sampling tables for n = n0 + lane, all 7 taps, in registers
  int   x0i[KK], x1i[KK];
  float wav[KK], wbv[KK];
#pragma unroll
  for (int kt = 0; kt < KK; ++kt) {
    float locv = Loc[(size_t)(n0 + lane) * KK + kt];
    int x0  = (int)floorf(locv);
    int x0c = min(max(x0, 0), LEN - 1);
    int x1c = min(max(x0 + 1, 0), LEN - 1);
    x0i[kt] = x0c; x1i[kt] = x1c;
    wav[kt] = (float)x1c - locv;
    wbv[kt] = locv - (float)x0c;
  }

  f32x4 acc[4][4];
#pragma unroll
  for (int a = 0; a < 4; ++a)
#pragma unroll
    for (int c = 0; c < 4; ++c) acc[a][c] = (f32x4){0.f, 0.f, 0.f, 0.f};

  const int mrow = lane & 15;
  const int quad = lane >> 4;

#pragma unroll
  for (int kt = 0; kt < KK; ++kt) {            // kt compile-time
    const int   xo0 = x0i[kt], xo1 = x1i[kt];
    const float wa = wav[kt],  wb = wbv[kt];

    __syncthreads();                           // prev chunk's readers done
    // ---- stage: thread covers n = n0+lane, i = 32*j + 8*w + m ----
#pragma unroll
    for (int j = 0; j < 8; ++j) {
      float fa[8], fb[8];
#pragma unroll
      for (int m = 0; m < 8; ++m) {
        const float* xr = Xb + ((size_t)(32 * j + 8 * w + m) << 13);
        fa[m] = xr[xo0];
        fb[m] = xr[xo1];
      }
      s16x8 v;
#pragma unroll
      for (int m = 0; m < 8; ++m)
        v[m] = (short)f2bf(wa * fa[m] + wb * fb[m]);
      *(s16x8*)&Il[lane][32 * j + 8 * w] = v;
    }
    __syncthreads();                           // staging visible

    // ---- consume: 8 K-steps of 32 ----
#pragma unroll
    for (int s = 0; s < 8; ++s) {
      s16x8 bf[4];
#pragma unroll
      for (int nt = 0; nt < 4; ++nt)
        bf[nt] = *(const s16x8*)&Il[nt * 16 + mrow][32 * s + quad * 8];
#pragma unroll
      for (int tt = 0; tt < 4; ++tt) {
        const s16x8 af = *(const s16x8*)(
            Wf + ((size_t)((((w * 4 + tt) * KK + kt) * 8 + s)) << 9) + (lane << 3));
        acc[tt][0] = __builtin_amdgcn_mfma_f32_16x16x32_bf16(af, bf[0], acc[tt][0], 0, 0, 0);
        acc[tt][1] = __builtin_amdgcn_mfma_f32_16x16x32_bf16(af, bf[1], acc[tt][1], 0, 0, 0);
        acc[tt][2] = __builtin_amdgcn_mfma_f32_16x16x32_bf16(af, bf[2], acc[tt][2], 0, 0, 0);
        acc[tt][3] = __builtin_amdgcn_mfma_f32_16x16x32_bf16(af, bf[3], acc[tt][3], 0, 0, 0);
      }
    }
  }

  // epilogue: D row m = quad*4+r (o), col = mrow (l)
  const int lbase = (n0 & (LEN - 1)) + mrow;
#pragma unroll
  for (int tt = 0; tt < 4; ++tt) {
    const int obase = (w * 4 + tt) * 16 + quad * 4;
#pragma unroll
    for (int r = 0; r < 4; ++r) {
      const int o = obase + r;
      const float bv = Bias[o];
      float* orow = Out + (((size_t)(b * COUT + o)) << 13) + lbase;
#pragma unroll
      for (int nt = 0; nt < 4; ++nt)
        orow[nt * 16] = acc[tt][nt][r] + bv;
    }
  }
}

extern "C" void kernel_launch(void* const* d_in, const int* in_sizes, int n_in,
                              void* d_out, int out_size, void* d_ws, size_t ws_size,
                              hipStream_t stream) {
  const float* X    = (const float*)d_in[0];   // (4,256,8192)
  const float* W    = (const float*)d_in[1];   // (256,256,7)
  const float* Bias = (const float*)d_in[2];   // (256,)
  const float* OW   = (const float*)d_in[3];   // (7,256,7)
  const float* OB   = (const float*)d_in[4];   // (7,)
  float* Out = (float*)d_out;                  // (4,256,8192)

  // ws layout: Loc (0.92 MB) | Wf (0.92 MB)  -- same footprint as round 2
  float* Loc = (float*)d_ws;
  unsigned short* Wf = (unsigned short*)(Loc + (size_t)NTOT * KK);

  init_loc<<<NTOT * KK / 256, 256, 0, stream>>>(OB, Loc);
  loc_partial<<<128 * 16, 256, 0, stream>>>(X, OW, Loc);
  wt_build<<<COUT * QTOT / 8 / 256, 256, 0, stream>>>(W, Wf);
  main_kernel<<<NTOT / 64, 256, 0, stream>>>(X, Wf, Bias, Loc, Out);
}

// Round 5
// 224.056 us; speedup vs baseline: 1.2447x; 1.2447x over previous
//
#include <hip/hip_runtime.h>
#include <hip/hip_bf16.h>

// DeformableConv1D: B=4, Cin=256, Cout=256, L=8192, K=7, stride=1, pad=3, dil=1
// out[b,o,l] = sum_{i,kt} w[o,i,kt] * interp(b, l, i, kt) + bias[o]
// loc[b,l,kt] = l + kt + (offset_conv(x)[b,l,kt] + offset_b[kt])
// interp = wa*x[b,i,x0c] + wb*x[b,i,x1c]  (clamped lerp, reference formula)
//
// Round 5:
//  - loc: single no-atomic kernel (wave-per-channel-group + LDS reduce).
//  - main: i-chunk ordering (32 channels x all 7 taps per chunk) so the
//    per-chunk X window (~9 KB) is L1-resident; contraction order within a
//    chunk is q = kt*32 + di, matched by rebuilt A-fragments.

#define B_    4
#define CIN   256
#define COUT  256
#define LEN   8192
#define KK    7
#define NTOT  (B_ * LEN)          // 32768
#define QTOT  (CIN * KK)          // 1792
#define LPITCH 232                // LDS row pitch (elems), 464 B, 16B-aligned

typedef short s16x8 __attribute__((ext_vector_type(8)));
typedef float f32x4 __attribute__((ext_vector_type(4)));

static __device__ __forceinline__ unsigned short f2bf(float f) {
  union { float f; unsigned u; } u; u.f = f;
  unsigned r = u.u + 0x7FFF + ((u.u >> 16) & 1);   // RNE (finite inputs)
  return (unsigned short)(r >> 16);
}

// ---------------------------------------------------------------------------
// Kernel 1: offset conv + base, NO atomics. Block = 64 l x 256 threads.
// Wave w sums channels [64w, 64w+64) for l = n0+lane; LDS reduce over waves;
// Loc[(n0+l)*7+k] = (l+k) + OB[k] + sum.
// ---------------------------------------------------------------------------
__global__ __launch_bounds__(256) void loc_kernel(
    const float* __restrict__ X, const float* __restrict__ OW,
    const float* __restrict__ OB, float* __restrict__ Loc) {
  __shared__ float red[4][64][8];              // 8192 B

  const int t    = threadIdx.x;
  const int lane = t & 63;
  const int w    = t >> 6;
  const int n0   = blockIdx.x << 6;            // grid 512
  const int b    = n0 >> 13;
  const int l    = (n0 & (LEN - 1)) + lane;
  const float* xb = X + ((size_t)b << 21);

  float acc[KK];
#pragma unroll
  for (int k = 0; k < KK; ++k) acc[k] = 0.0f;

#pragma unroll 4
  for (int ii = 0; ii < 64; ++ii) {
    const int i = w * 64 + ii;
    const float* xr = xb + ((size_t)i << 13);
    float xv[KK];
#pragma unroll
    for (int j = 0; j < KK; ++j) {
      int pos = l + j - 3;
      xv[j] = ((unsigned)pos < LEN) ? xr[pos] : 0.0f;
    }
#pragma unroll
    for (int k = 0; k < KK; ++k)
#pragma unroll
      for (int j = 0; j < KK; ++j)
        acc[k] += xv[j] * OW[(k * CIN + i) * KK + j];   // wave-uniform i
  }
#pragma unroll
  for (int k = 0; k < KK; ++k) red[w][lane][k] = acc[k];
  __syncthreads();

  for (int e = t; e < 64 * KK; e += 256) {
    int ll = e / KK;
    int k  = e - ll * KK;
    float s = (float)((n0 & (LEN - 1)) + ll + k) + OB[k];
#pragma unroll
    for (int ww = 0; ww < 4; ++ww) s += red[ww][ll][k];
    Loc[(size_t)(n0 + ll) * KK + k] = s;
  }
}

// ---------------------------------------------------------------------------
// Kernel 2: weights -> bf16 A-fragments matching i-chunk order.
// frag f = (ot*8 + c)*7 + s; elem lane*8+j holds
//   W[o = ot*16 + (lane&15)][(i = c*32 + (lane>>4)*8 + j)*7 + (kt = s)]
// ---------------------------------------------------------------------------
__global__ __launch_bounds__(256) void wt_build(
    const float* __restrict__ W, unsigned short* __restrict__ Wf) {
  int tid  = blockIdx.x * 256 + threadIdx.x;   // grid 224 -> 57344
  int lane = tid & 63;
  int f    = tid >> 6;                         // 0..895
  int s    = f % KK;                           // kt
  int c    = (f / KK) & 7;                     // i-chunk
  int ot   = f / (KK * 8);                     // 0..15
  int o    = ot * 16 + (lane & 15);
  int ib   = c * 32 + (lane >> 4) * 8;
  s16x8 v;
#pragma unroll
  for (int j = 0; j < 8; ++j)
    v[j] = (short)f2bf(W[(size_t)o * QTOT + (ib + j) * KK + s]);
  *(s16x8*)(Wf + (size_t)tid * 8) = v;
}

// ---------------------------------------------------------------------------
// Kernel 3: main MFMA GEMM. Block = 256(o) x 64(n), 4 waves, grid 512.
// 8 i-chunks of 32 channels. Per chunk: stage interp for all 7 taps
// (slots (n,kt): slot = t and t+256; per slot 32 i x 2 gathers, 4 b128 LDS
// writes), barrier, 7 MFMA K-steps (step s = tap s: 4 nt x 4 tt mfma),
// barrier. X window per chunk ~9 KB -> L1-resident gathers.
// ---------------------------------------------------------------------------
__global__ __launch_bounds__(256, 2) void main_kernel(
    const float* __restrict__ X, const unsigned short* __restrict__ Wf,
    const float* __restrict__ Bias, const float* __restrict__ Loc,
    float* __restrict__ Out) {
  __shared__ unsigned short Il[64][LPITCH];    // 29696 B

  const int t    = threadIdx.x;
  const int lane = t & 63;
  const int w    = t >> 6;
  const int n0   = blockIdx.x << 6;            // grid 512
  const int b    = n0 >> 13;
  const float* Xb = X + ((size_t)b << 21);

  // slot 1: (nl1, kt1) = (t&63, t>>6); slot 2: t+256 -> (t&63, 4 + (t>>6)),
  // valid for t < 192. Sampling params in registers.
  const int nl1 = lane, kt1 = w;
  const int kt2 = 4 + w;
  const bool has2 = (t < 192);

  int x0a, x1a; float waa, wba;
  {
    float locv = Loc[(size_t)(n0 + nl1) * KK + kt1];
    int x0  = (int)floorf(locv);
    x0a = min(max(x0, 0), LEN - 1);
    x1a = min(max(x0 + 1, 0), LEN - 1);
    waa = (float)x1a - locv;
    wba = locv - (float)x0a;
  }
  int x0b2 = 0, x1b2 = 0; float wab = 0.f, wbb = 0.f;
  if (has2) {
    float locv = Loc[(size_t)(n0 + nl1) * KK + kt2];
    int x0  = (int)floorf(locv);
    x0b2 = min(max(x0, 0), LEN - 1);
    x1b2 = min(max(x0 + 1, 0), LEN - 1);
    wab = (float)x1b2 - locv;
    wbb = locv - (float)x0b2;
  }

  f32x4 acc[4][4];
#pragma unroll
  for (int a = 0; a < 4; ++a)
#pragma unroll
    for (int cc = 0; cc < 4; ++cc) acc[a][cc] = (f32x4){0.f, 0.f, 0.f, 0.f};

  const int mrow = lane & 15;
  const int quad = lane >> 4;

  for (int c = 0; c < 8; ++c) {                // i-chunks
    const int i0 = c * 32;
    __syncthreads();                           // prev chunk's readers done

    // ---- stage slot 1: 32 i, taps kt1 ----
    {
      s16x8 vv[4];
#pragma unroll
      for (int g = 0; g < 4; ++g) {
#pragma unroll
        for (int m = 0; m < 8; ++m) {
          const float* xr = Xb + ((size_t)(i0 + g * 8 + m) << 13);
          float fa = xr[x0a], fb = xr[x1a];
          vv[g][m] = (short)f2bf(waa * fa + wba * fb);
        }
      }
#pragma unroll
      for (int g = 0; g < 4; ++g)
        *(s16x8*)&Il[nl1][kt1 * 32 + g * 8] = vv[g];
    }
    // ---- stage slot 2 ----
    if (has2) {
      s16x8 vv[4];
#pragma unroll
      for (int g = 0; g < 4; ++g) {
#pragma unroll
        for (int m = 0; m < 8; ++m) {
          const float* xr = Xb + ((size_t)(i0 + g * 8 + m) << 13);
          float fa = xr[x0b2], fb = xr[x1b2];
          vv[g][m] = (short)f2bf(wab * fa + wbb * fb);
        }
      }
#pragma unroll
      for (int g = 0; g < 4; ++g)
        *(s16x8*)&Il[nl1][kt2 * 32 + g * 8] = vv[g];
    }
    __syncthreads();                           // staging visible

    // ---- consume: 7 K-steps (step s = tap s), K=32 each ----
#pragma unroll
    for (int s = 0; s < KK; ++s) {
      s16x8 bf[4];
#pragma unroll
      for (int nt = 0; nt < 4; ++nt)
        bf[nt] = *(const s16x8*)&Il[nt * 16 + mrow][s * 32 + quad * 8];
#pragma unroll
      for (int tt = 0; tt < 4; ++tt) {
        const s16x8 af = *(const s16x8*)(
            Wf + ((size_t)(((w * 4 + tt) * 8 + c) * KK + s) << 9) + (lane << 3));
        acc[tt][0] = __builtin_amdgcn_mfma_f32_16x16x32_bf16(af, bf[0], acc[tt][0], 0, 0, 0);
        acc[tt][1] = __builtin_amdgcn_mfma_f32_16x16x32_bf16(af, bf[1], acc[tt][1], 0, 0, 0);
        acc[tt][2] = __builtin_amdgcn_mfma_f32_16x16x32_bf16(af, bf[2], acc[tt][2], 0, 0, 0);
        acc[tt][3] = __builtin_amdgcn_mfma_f32_16x16x32_bf16(af, bf[3], acc[tt][3], 0, 0, 0);
      }
    }
  }

  // epilogue: D row m = quad*4+r (o), col = mrow (l)
  const int lbase = (n0 & (LEN - 1)) + mrow;
#pragma unroll
  for (int tt = 0; tt < 4; ++tt) {
    const int obase = (w * 4 + tt) * 16 + quad * 4;
#pragma unroll
    for (int r = 0; r < 4; ++r) {
      const int o = obase + r;
      const float bv = Bias[o];
      float* orow = Out + (((size_t)(b * COUT + o)) << 13) + lbase;
#pragma unroll
      for (int nt = 0; nt < 4; ++nt)
        orow[nt * 16] = acc[tt][nt][r] + bv;
    }
  }
}

extern "C" void kernel_launch(void* const* d_in, const int* in_sizes, int n_in,
                              void* d_out, int out_size, void* d_ws, size_t ws_size,
                              hipStream_t stream) {
  const float* X    = (const float*)d_in[0];   // (4,256,8192)
  const float* W    = (const float*)d_in[1];   // (256,256,7)
  const float* Bias = (const float*)d_in[2];   // (256,)
  const float* OW   = (const float*)d_in[3];   // (7,256,7)
  const float* OB   = (const float*)d_in[4];   // (7,)
  float* Out = (float*)d_out;                  // (4,256,8192)

  // ws layout: Loc (0.92 MB) | Wf (0.92 MB)
  float* Loc = (float*)d_ws;
  unsigned short* Wf = (unsigned short*)(Loc + (size_t)NTOT * KK);

  loc_kernel<<<NTOT / 64, 256, 0, stream>>>(X, OW, OB, Loc);
  wt_build<<<COUT * QTOT / 8 / 256, 256, 0, stream>>>(W, Wf);
  main_kernel<<<NTOT / 64, 256, 0, stream>>>(X, Wf, Bias, Loc, Out);
}